// Round 9
// baseline (170.529 us; speedup 1.0000x reference)
//
#include <hip/hip_runtime.h>

#define B_DIM 2
#define H_DIM 16
#define S_DIM 2048
#define D_DIM 64

constexpr int KB = 64;             // keys per tile
constexpr int NT = S_DIM / KB;     // 32 key tiles
constexpr float CL2E = 0.18033688011112042f;  // (1/sqrt(64)) * log2(e)

typedef __attribute__((ext_vector_type(8))) short short8;   // 8 bf16
typedef __attribute__((ext_vector_type(4))) float f32x4;
typedef __attribute__((ext_vector_type(2))) unsigned uint2v;

__device__ __forceinline__ unsigned pkbf(float lo, float hi) {
  unsigned r;
  asm("v_cvt_pk_bf16_f32 %0, %1, %2" : "=v"(r) : "v"(lo), "v"(hi));
  return r;
}

__device__ __forceinline__ float fexp2(float x) {
  float r;
  asm("v_exp_f32 %0, %1" : "=v"(r) : "v"(x));
  return r;
}

// drain LDS ops (cross-wave visibility) but NOT vmcnt — prefetch global
// loads stay in flight across the barrier (T14).
__device__ __forceinline__ void barrier_lds() {
  asm volatile("s_waitcnt lgkmcnt(0)" ::: "memory");
  __builtin_amdgcn_s_barrier();
  asm volatile("" ::: "memory");
}

// ===================== kernel A: row-sum -> Lm = -log2(sum) =====================
// 16 q-rows per wave, QB=64, grid 1024: high occupancy (16 KB LDS, ~60 VGPR),
// no V/P staging, no global stores except the tiny Lm vector.
__global__ __launch_bounds__(256, 4)
void rowsum_kernel(const float* __restrict__ Qp, const float* __restrict__ Kp,
                   const int* __restrict__ maskp, float* __restrict__ LmOut)
{
  __shared__ __align__(16) unsigned short sK[2][KB * 64];   // [buf][key][d] bf16, swizzled, col-masked

  const int tid  = threadIdx.x;
  const int wave = tid >> 6;
  const int lane = tid & 63;
  const int c = lane & 15;
  const int g = lane >> 4;

  // XCD swizzle (1024 % 8 == 0)
  const int bid = (blockIdx.x & 7) * 128 + (blockIdx.x >> 3);
  const int bh = bid >> 5;
  const int qt = bid & 31;
  const int q0 = qt * 64 + wave * 16;
  const size_t bhS = (size_t)bh * S_DIM;

  const int key = tid >> 2;
  const int dq  = (tid & 3) << 4;

  short8 qf[2];
  #pragma unroll
  for (int kk = 0; kk < 2; ++kk) {
    const float* src = Qp + (bhS + (size_t)(q0 + c)) * D_DIM + kk*32 + g*8;
    float4 a = ((const float4*)src)[0];
    float4 b = ((const float4*)src)[1];
    union { unsigned u[4]; short8 s; } w;
    w.u[0] = pkbf(a.x, a.y); w.u[1] = pkbf(a.z, a.w);
    w.u[2] = pkbf(b.x, b.y); w.u[3] = pkbf(b.z, b.w);
    qf[kk] = w.s;
  }

  const float rvS = maskp[bhS + q0 + c] ? CL2E : 0.0f;

  float4 kr0, kr1, kr2, kr3;
  unsigned kmr;
  auto load_k = [&](int kt_) {
    const float* s = Kp + (bhS + (size_t)(kt_ * KB + key)) * D_DIM + dq;
    kr0 = ((const float4*)s)[0]; kr1 = ((const float4*)s)[1];
    kr2 = ((const float4*)s)[2]; kr3 = ((const float4*)s)[3];
    kmr = maskp[bhS + kt_ * KB + key] ? 0xFFFFFFFFu : 0u;
  };
  auto write_k = [&](int buf) {
    union { unsigned u[4]; short8 s; } w0, w1;
    w0.u[0] = pkbf(kr0.x, kr0.y) & kmr; w0.u[1] = pkbf(kr0.z, kr0.w) & kmr;
    w0.u[2] = pkbf(kr1.x, kr1.y) & kmr; w0.u[3] = pkbf(kr1.z, kr1.w) & kmr;
    w1.u[0] = pkbf(kr2.x, kr2.y) & kmr; w1.u[1] = pkbf(kr2.z, kr2.w) & kmr;
    w1.u[2] = pkbf(kr3.x, kr3.y) & kmr; w1.u[3] = pkbf(kr3.z, kr3.w) & kmr;
    const int sw = (key & 7) << 3;
    *(short8*)&sK[buf][key * 64 + (dq ^ sw)]       = w0.s;
    *(short8*)&sK[buf][key * 64 + ((dq + 8) ^ sw)] = w1.s;
  };

  float lsum = 0.0f;
  load_k(0);
  for (int kt = 0; kt < NT; ++kt) {
    const int cur = kt & 1;
    write_k(cur);
    if (kt + 1 < NT) load_k(kt + 1);
    barrier_lds();

    short8 kf[4][2];
    #pragma unroll
    for (int n = 0; n < 4; ++n) {
      const int k2 = n*16 + c;
      const int sw = (c & 7) << 3;
      #pragma unroll
      for (int kk = 0; kk < 2; ++kk)
        kf[n][kk] = *(const short8*)&sK[cur][k2*64 + ((kk*32 + g*8) ^ sw)];
    }

    f32x4 sacc[4];
    #pragma unroll
    for (int n = 0; n < 4; ++n) sacc[n] = 0.0f;
    __builtin_amdgcn_s_setprio(1);
    #pragma unroll
    for (int n = 0; n < 4; ++n)
      #pragma unroll
      for (int kk = 0; kk < 2; ++kk)
        sacc[n] = __builtin_amdgcn_mfma_f32_16x16x32_bf16(kf[n][kk], qf[kk], sacc[n], 0, 0, 0);
    __builtin_amdgcn_s_setprio(0);

    #pragma unroll
    for (int n = 0; n < 4; ++n)
      #pragma unroll
      for (int e = 0; e < 4; ++e)
        lsum += fexp2(sacc[n][e] * rvS);
  }

  float v = lsum;
  v += __shfl_xor(v, 16);
  v += __shfl_xor(v, 32);
  if (g == 0) LmOut[bhS + q0 + c] = -__log2f(v);
}

// ===================== kernel B: recompute, write attn, PV =====================
// R7's pass 2 verbatim; Lm loaded from workspace.
__global__ __launch_bounds__(256, 2)
void sdpa_kernel(const float* __restrict__ Qp, const float* __restrict__ Kp,
                 const float* __restrict__ Vp, const int* __restrict__ maskp,
                 const float* __restrict__ LmIn,
                 float* __restrict__ ctx, float* __restrict__ attn)
{
  __shared__ __align__(16) unsigned short sK[2][KB * 64];      // [buf][key][d] bf16, swizzled, col-masked
  __shared__ __align__(16) unsigned short sV[2][64 * KB];      // [buf][d][key] bf16, swizzled
  __shared__ __align__(16) unsigned short sP[2][4][32 * 64];   // [buf][wave] P [q][key] bf16, swizzled

  const int tid  = threadIdx.x;
  const int wave = tid >> 6;
  const int lane = tid & 63;
  const int c = lane & 15;
  const int g = lane >> 4;

  // XCD swizzle (512 % 8 == 0)
  const int bid = (blockIdx.x & 7) * 64 + (blockIdx.x >> 3);
  const int bh = bid >> 4;
  const int qt = bid & 15;
  const int q0 = qt * 128 + wave * 32;
  const size_t bhS = (size_t)bh * S_DIM;

  const int key = tid >> 2;
  const int dq  = (tid & 3) << 4;
  const int kp  = (tid & 31) << 1;
  const int dq8 = (tid >> 5) << 3;

  short8 qf[2][2];
  #pragma unroll
  for (int m = 0; m < 2; ++m)
    #pragma unroll
    for (int kk = 0; kk < 2; ++kk) {
      const float* src = Qp + (bhS + (size_t)(q0 + m*16 + c)) * D_DIM + kk*32 + g*8;
      float4 a = ((const float4*)src)[0];
      float4 b = ((const float4*)src)[1];
      union { unsigned u[4]; short8 s; } w;
      w.u[0] = pkbf(a.x, a.y); w.u[1] = pkbf(a.z, a.w);
      w.u[2] = pkbf(b.x, b.y); w.u[3] = pkbf(b.z, b.w);
      qf[m][kk] = w.s;
    }

  float rvS[2], Lm[2];
  #pragma unroll
  for (int m = 0; m < 2; ++m) {
    rvS[m] = maskp[bhS + q0 + m*16 + c] ? CL2E : 0.0f;
    Lm[m]  = LmIn[bhS + q0 + m*16 + c];
  }

  float4 kr0, kr1, kr2, kr3;
  float4 vA0, vA1, vB0, vB1;
  unsigned kmr;

  auto load_k = [&](int kt_) {
    const float* s = Kp + (bhS + (size_t)(kt_ * KB + key)) * D_DIM + dq;
    kr0 = ((const float4*)s)[0]; kr1 = ((const float4*)s)[1];
    kr2 = ((const float4*)s)[2]; kr3 = ((const float4*)s)[3];
    kmr = maskp[bhS + kt_ * KB + key] ? 0xFFFFFFFFu : 0u;
  };
  auto load_v = [&](int kt_) {
    const float* s0 = Vp + (bhS + (size_t)(kt_ * KB + kp)) * D_DIM + dq8;
    vA0 = ((const float4*)s0)[0]; vA1 = ((const float4*)s0)[1];
    vB0 = ((const float4*)(s0 + D_DIM))[0]; vB1 = ((const float4*)(s0 + D_DIM))[1];
  };
  auto write_k = [&](int buf) {
    union { unsigned u[4]; short8 s; } w0, w1;
    w0.u[0] = pkbf(kr0.x, kr0.y) & kmr; w0.u[1] = pkbf(kr0.z, kr0.w) & kmr;
    w0.u[2] = pkbf(kr1.x, kr1.y) & kmr; w0.u[3] = pkbf(kr1.z, kr1.w) & kmr;
    w1.u[0] = pkbf(kr2.x, kr2.y) & kmr; w1.u[1] = pkbf(kr2.z, kr2.w) & kmr;
    w1.u[2] = pkbf(kr3.x, kr3.y) & kmr; w1.u[3] = pkbf(kr3.z, kr3.w) & kmr;
    const int sw = (key & 7) << 3;
    *(short8*)&sK[buf][key * 64 + (dq ^ sw)]       = w0.s;
    *(short8*)&sK[buf][key * 64 + ((dq + 8) ^ sw)] = w1.s;
  };
  auto write_v = [&](int buf) {
    float fa[8], fb[8];
    *(float4*)&fa[0] = vA0; *(float4*)&fa[4] = vA1;
    *(float4*)&fb[0] = vB0; *(float4*)&fb[4] = vB1;
    #pragma unroll
    for (int e = 0; e < 8; ++e) {
      const int d = dq8 + e;
      *(unsigned*)&sV[buf][d * KB + (kp ^ ((d & 7) << 3))] = pkbf(fa[e], fb[e]);
    }
  };

  f32x4 oacc[2][4];
  #pragma unroll
  for (int m = 0; m < 2; ++m)
    #pragma unroll
    for (int n = 0; n < 4; ++n) oacc[m][n] = 0.0f;

  const int rh  = lane >> 4;
  const int c16 = lane & 15;
  float* const abase = attn + (bhS + (size_t)q0) * S_DIM;

  auto copyout = [&](int pb, int kt_) {
    const unsigned short* const Pp = sP[pb][wave];
    float* const at = abase + kt_*KB;
    #pragma unroll
    for (int j = 0; j < 8; ++j) {
      const int rr = j*4 + rh;
      const int p8 = (c16 >> 1) ^ (rr & 7);
      uint2v u = *(const uint2v*)&Pp[rr*64 + p8*8 + (c16 & 1)*4];
      union { unsigned iu; float f; } t0, t1, t2, t3;
      t0.iu = u.x << 16; t1.iu = u.x & 0xFFFF0000u;
      t2.iu = u.y << 16; t3.iu = u.y & 0xFFFF0000u;
      f32x4 o; o[0] = t0.f; o[1] = t1.f; o[2] = t2.f; o[3] = t3.f;
      __builtin_nontemporal_store(o, (f32x4*)(at + (size_t)rr * S_DIM + c16*4));
    }
  };

  load_k(0); load_v(0);
  for (int kt = 0; kt < NT; ++kt) {
    const int cur = kt & 1;
    write_k(cur);
    write_v(cur);
    if (kt + 1 < NT) { load_k(kt + 1); load_v(kt + 1); }
    barrier_lds();

    short8 kf[4][2];
    #pragma unroll
    for (int n = 0; n < 4; ++n) {
      const int k2 = n*16 + c;
      const int sw = (c & 7) << 3;
      #pragma unroll
      for (int kk = 0; kk < 2; ++kk)
        kf[n][kk] = *(const short8*)&sK[cur][k2*64 + ((kk*32 + g*8) ^ sw)];
    }

    f32x4 sacc[4][2];
    #pragma unroll
    for (int n = 0; n < 4; ++n)
      #pragma unroll
      for (int m = 0; m < 2; ++m) sacc[n][m] = 0.0f;
    __builtin_amdgcn_s_setprio(1);
    #pragma unroll
    for (int n = 0; n < 4; ++n)
      #pragma unroll
      for (int m = 0; m < 2; ++m)
        #pragma unroll
        for (int kk = 0; kk < 2; ++kk)
          sacc[n][m] = __builtin_amdgcn_mfma_f32_16x16x32_bf16(kf[n][kk], qf[m][kk], sacc[n][m], 0, 0, 0);
    __builtin_amdgcn_s_setprio(0);

    // deferred copy-out of PREVIOUS tile's attn
    if (kt > 0) copyout(cur ^ 1, kt - 1);

    unsigned short* const myP = sP[cur][wave];
    #pragma unroll
    for (int m = 0; m < 2; ++m) {
      #pragma unroll
      for (int n = 0; n < 4; ++n) {
        f32x4 pv;
        #pragma unroll
        for (int e = 0; e < 4; ++e)
          pv[e] = fexp2(__builtin_fmaf(sacc[n][m][e], rvS[m], Lm[m]));
        const int row = m*16 + c;
        const int swk = (n*16 + g*4) ^ ((c & 7) << 3);
        uint2v pr; pr.x = pkbf(pv[0], pv[1]); pr.y = pkbf(pv[2], pv[3]);
        *(uint2v*)&myP[row*64 + swk] = pr;
      }
    }

    short8 pf[2][2];
    #pragma unroll
    for (int m = 0; m < 2; ++m) {
      const int row = m*16 + c;
      const int sw = (c & 7) << 3;
      #pragma unroll
      for (int kk = 0; kk < 2; ++kk)
        pf[m][kk] = *(const short8*)&myP[row*64 + ((kk*32 + g*8) ^ sw)];
    }
    short8 vf[4][2];
    #pragma unroll
    for (int n = 0; n < 4; ++n) {
      const int d = n*16 + c;
      const int sw = (d & 7) << 3;
      #pragma unroll
      for (int kk = 0; kk < 2; ++kk)
        vf[n][kk] = *(const short8*)&sV[cur][d*KB + ((kk*32 + g*8) ^ sw)];
    }
    __builtin_amdgcn_s_setprio(1);
    #pragma unroll
    for (int m = 0; m < 2; ++m)
      #pragma unroll
      for (int n = 0; n < 4; ++n)
        #pragma unroll
        for (int kk = 0; kk < 2; ++kk)
          oacc[m][n] = __builtin_amdgcn_mfma_f32_16x16x32_bf16(pf[m][kk], vf[n][kk], oacc[m][n], 0, 0, 0);
    __builtin_amdgcn_s_setprio(0);
  }

  copyout((NT - 1) & 1, NT - 1);

  #pragma unroll
  for (int m = 0; m < 2; ++m)
    #pragma unroll
    for (int n = 0; n < 4; ++n)
      #pragma unroll
      for (int e = 0; e < 4; ++e) {
        const int rl = m*16 + g*4 + e;
        ctx[(bhS + (size_t)(q0 + rl)) * D_DIM + (size_t)(n*16 + c)] = oacc[m][n][e];
      }
}

extern "C" void kernel_launch(void* const* d_in, const int* in_sizes, int n_in,
                              void* d_out, int out_size, void* d_ws, size_t ws_size,
                              hipStream_t stream) {
  const float* Q = (const float*)d_in[0];
  const float* K = (const float*)d_in[1];
  const float* V = (const float*)d_in[2];
  const int*   M = (const int*)d_in[3];
  float* ctx  = (float*)d_out;
  float* attn = ctx + (size_t)B_DIM * H_DIM * S_DIM * D_DIM;
  float* Lms  = (float*)d_ws;                       // B*H*S floats = 256 KB

  rowsum_kernel<<<dim3(B_DIM * H_DIM * (S_DIM / 64)), 256, 0, stream>>>(Q, K, M, Lms);
  sdpa_kernel<<<dim3(B_DIM * H_DIM * (S_DIM / 128)), 256, 0, stream>>>(Q, K, V, M, Lms, ctx, attn);
}

// Round 10
// 145.789 us; speedup vs baseline: 1.1697x; 1.1697x over previous
//
#include <hip/hip_runtime.h>

#define B_DIM 2
#define H_DIM 16
#define S_DIM 2048
#define D_DIM 64

constexpr int KB = 64;             // keys per tile
constexpr int NT = S_DIM / KB;     // 32 key tiles
constexpr float CL2E = 0.18033688011112042f;  // (1/sqrt(64)) * log2(e)

typedef __attribute__((ext_vector_type(8))) short short8;   // 8 bf16
typedef __attribute__((ext_vector_type(4))) float f32x4;
typedef __attribute__((ext_vector_type(2))) unsigned uint2v;

__device__ __forceinline__ unsigned pkbf(float lo, float hi) {
  unsigned r;
  asm("v_cvt_pk_bf16_f32 %0, %1, %2" : "=v"(r) : "v"(lo), "v"(hi));
  return r;
}

__device__ __forceinline__ float fexp2(float x) {
  float r;
  asm("v_exp_f32 %0, %1" : "=v"(r) : "v"(x));
  return r;
}

// drain LDS ops (cross-wave visibility) but NOT vmcnt — prefetch global
// loads stay in flight across the barrier (T14).
__device__ __forceinline__ void barrier_lds() {
  asm volatile("s_waitcnt lgkmcnt(0)" ::: "memory");
  __builtin_amdgcn_s_barrier();
  asm volatile("" ::: "memory");
}

// One block = 512 threads (8 waves) = one 256-row q-super-tile: X = rows
// [0,128), Y = rows [128,256); each wave owns 16 rows of X and 16 of Y.
// Phase A: pass1(X).  Phase B: pass2(X) fused with pass1(Y) per K-tile
// (shared staged K + shared kf fragments; X's stores drain under Y's
// compute).  Phase C: pass2(Y).
__global__ __launch_bounds__(512, 2)
void sdpa_kernel(const float* __restrict__ Qp, const float* __restrict__ Kp,
                 const float* __restrict__ Vp, const int* __restrict__ maskp,
                 float* __restrict__ ctx, float* __restrict__ attn)
{
  __shared__ __align__(16) unsigned short sK[2][KB * 64];   // [buf][key][d] bf16, swizzled, col-masked
  __shared__ __align__(16) unsigned short sV[2][64 * KB];   // [buf][d][key] bf16, swizzled
  __shared__ __align__(16) unsigned short sP[8][16 * 64];   // per-wave P [q16][key] bf16, swizzled

  const int tid  = threadIdx.x;
  const int wave = tid >> 6;
  const int lane = tid & 63;
  const int c = lane & 15;      // fragment col (q within 16)
  const int g = lane >> 4;      // fragment key-subgroup

  // XCD-aware bijective swizzle (256 % 8 == 0)
  const int bid = (blockIdx.x & 7) * 32 + (blockIdx.x >> 3);
  const int bh = bid >> 3;            // 8 super-tiles per (b,h)
  const int qt = bid & 7;
  const int q0x = qt * 256 + wave * 16;
  const int q0y = q0x + 128;
  const size_t bhS = (size_t)bh * S_DIM;

  // staging coords (512 threads)
  const int keyk = tid >> 3;              // K: 0..63
  const int dqk  = (tid & 7) << 3;        // K: d octet 0..56
  const int kpv  = (tid & 31) << 1;       // V: even key 0..62
  const int d4   = (tid >> 5) << 2;       // V: d quad 0..60

  // ---- Q fragments (B-operand): col=q=lane&15, k = kk*32 + g*8 + j ----
  short8 qfX[2], qfY[2];
  #pragma unroll
  for (int kk = 0; kk < 2; ++kk) {
    const float* sx = Qp + (bhS + (size_t)(q0x + c)) * D_DIM + kk*32 + g*8;
    float4 a = ((const float4*)sx)[0];
    float4 b = ((const float4*)sx)[1];
    union { unsigned u[4]; short8 s; } w;
    w.u[0] = pkbf(a.x, a.y); w.u[1] = pkbf(a.z, a.w);
    w.u[2] = pkbf(b.x, b.y); w.u[3] = pkbf(b.z, b.w);
    qfX[kk] = w.s;
    const float* sy = Qp + (bhS + (size_t)(q0y + c)) * D_DIM + kk*32 + g*8;
    float4 ay = ((const float4*)sy)[0];
    float4 by = ((const float4*)sy)[1];
    w.u[0] = pkbf(ay.x, ay.y); w.u[1] = pkbf(ay.z, ay.w);
    w.u[2] = pkbf(by.x, by.y); w.u[3] = pkbf(by.z, by.w);
    qfY[kk] = w.s;
  }

  const float rvSX = maskp[bhS + q0x + c] ? CL2E : 0.0f;
  const float rvSY = maskp[bhS + q0y + c] ? CL2E : 0.0f;

  // prefetch registers
  float4 kA, kB;            // K: 8 floats
  float4 vA, vB;            // V: 2 keys x 4 d
  unsigned kmr;

  auto load_k = [&](int kt_) {
    const float* s = Kp + (bhS + (size_t)(kt_ * KB + keyk)) * D_DIM + dqk;
    kA = ((const float4*)s)[0]; kB = ((const float4*)s)[1];
    kmr = maskp[bhS + kt_ * KB + keyk] ? 0xFFFFFFFFu : 0u;
  };
  auto load_v = [&](int kt_) {
    const float* s0 = Vp + (bhS + (size_t)(kt_ * KB + kpv)) * D_DIM + d4;
    vA = *(const float4*)s0;
    vB = *(const float4*)(s0 + D_DIM);
  };
  // col-masked K staging: masked key rows stored as exact zeros -> sacc==0
  // -> p = exp2(0 + Lm) = 1/sum, exactly the reference's value.
  auto write_k = [&](int buf) {
    union { unsigned u[4]; short8 s; } w;
    w.u[0] = pkbf(kA.x, kA.y) & kmr; w.u[1] = pkbf(kA.z, kA.w) & kmr;
    w.u[2] = pkbf(kB.x, kB.y) & kmr; w.u[3] = pkbf(kB.z, kB.w) & kmr;
    *(short8*)&sK[buf][keyk * 64 + (dqk ^ ((keyk & 7) << 3))] = w.s;
  };
  auto write_v = [&](int buf) {
    float fa[4], fb[4];
    *(float4*)fa = vA; *(float4*)fb = vB;
    #pragma unroll
    for (int e = 0; e < 4; ++e) {
      const int d = d4 + e;
      *(unsigned*)&sV[buf][d * KB + (kpv ^ ((d & 7) << 3))] = pkbf(fa[e], fb[e]);
    }
  };

  unsigned short* const myP = sP[wave];
  const int rh  = lane >> 4;
  const int c16 = lane & 15;
  float* const abx = attn + (bhS + (size_t)q0x) * S_DIM;
  float* const aby = attn + (bhS + (size_t)q0y) * S_DIM;

  // attn copy-out from sP: 4 rows x 256B = 1KB contiguous per store
  auto copyout = [&](float* ab, int kt_) {
    float* const at = ab + kt_*KB;
    #pragma unroll
    for (int j = 0; j < 4; ++j) {
      const int rr = j*4 + rh;
      const int p8 = (c16 >> 1) ^ (rr & 7);
      uint2v u = *(const uint2v*)&myP[rr*64 + p8*8 + (c16 & 1)*4];
      union { unsigned iu; float f; } t0, t1, t2, t3;
      t0.iu = u.x << 16; t1.iu = u.x & 0xFFFF0000u;
      t2.iu = u.y << 16; t3.iu = u.y & 0xFFFF0000u;
      f32x4 o; o[0] = t0.f; o[1] = t1.f; o[2] = t2.f; o[3] = t3.f;
      __builtin_nontemporal_store(o, (f32x4*)(at + (size_t)rr * S_DIM + c16*4));
    }
  };

  auto read_kf = [&](int cur, short8 (&kf)[4][2]) {
    #pragma unroll
    for (int n = 0; n < 4; ++n) {
      const int k2 = n*16 + c;
      const int sw = (c & 7) << 3;
      #pragma unroll
      for (int kk = 0; kk < 2; ++kk)
        kf[n][kk] = *(const short8*)&sK[cur][k2*64 + ((kk*32 + g*8) ^ sw)];
    }
  };

  // ================= phase A: pass1(X) =================
  float lsumX = 0.0f;
  load_k(0);
  for (int kt = 0; kt < NT; ++kt) {
    const int cur = kt & 1;
    write_k(cur);
    if (kt + 1 < NT) load_k(kt + 1);
    else { load_k(0); load_v(0); }       // prefetch for phase B
    barrier_lds();

    short8 kf[4][2];
    read_kf(cur, kf);
    f32x4 sacc[4];
    #pragma unroll
    for (int n = 0; n < 4; ++n) sacc[n] = 0.0f;
    __builtin_amdgcn_s_setprio(1);
    #pragma unroll
    for (int n = 0; n < 4; ++n)
      #pragma unroll
      for (int kk = 0; kk < 2; ++kk)
        sacc[n] = __builtin_amdgcn_mfma_f32_16x16x32_bf16(kf[n][kk], qfX[kk], sacc[n], 0, 0, 0);
    __builtin_amdgcn_s_setprio(0);
    #pragma unroll
    for (int n = 0; n < 4; ++n)
      #pragma unroll
      for (int e = 0; e < 4; ++e)
        lsumX += fexp2(sacc[n][e] * rvSX);
  }
  float LmX;
  {
    float v = lsumX;
    v += __shfl_xor(v, 16);
    v += __shfl_xor(v, 32);
    LmX = -__log2f(v);
  }

  // ================= phase B: pass2(X) || pass1(Y) =================
  f32x4 oaccX[4];
  #pragma unroll
  for (int n = 0; n < 4; ++n) oaccX[n] = 0.0f;
  float lsumY = 0.0f;

  for (int kt = 0; kt < NT; ++kt) {
    const int cur = kt & 1;
    write_k(cur);
    write_v(cur);
    if (kt + 1 < NT) { load_k(kt + 1); load_v(kt + 1); }
    else { load_k(0); load_v(0); }       // prefetch for phase C
    barrier_lds();

    short8 kf[4][2];
    read_kf(cur, kf);                    // shared by X-recompute and Y-sum

    f32x4 saccX[4], saccY[4];
    #pragma unroll
    for (int n = 0; n < 4; ++n) { saccX[n] = 0.0f; saccY[n] = 0.0f; }
    __builtin_amdgcn_s_setprio(1);
    #pragma unroll
    for (int n = 0; n < 4; ++n)
      #pragma unroll
      for (int kk = 0; kk < 2; ++kk) {
        saccX[n] = __builtin_amdgcn_mfma_f32_16x16x32_bf16(kf[n][kk], qfX[kk], saccX[n], 0, 0, 0);
        saccY[n] = __builtin_amdgcn_mfma_f32_16x16x32_bf16(kf[n][kk], qfY[kk], saccY[n], 0, 0, 0);
      }
    __builtin_amdgcn_s_setprio(0);

    // X: p = exp2(s*rvS + Lm) -> bf16 into wave-private sP (swizzled)
    #pragma unroll
    for (int n = 0; n < 4; ++n) {
      f32x4 pv;
      #pragma unroll
      for (int e = 0; e < 4; ++e)
        pv[e] = fexp2(__builtin_fmaf(saccX[n][e], rvSX, LmX));
      const int swk = (n*16 + g*4) ^ ((c & 7) << 3);
      uint2v pr; pr.x = pkbf(pv[0], pv[1]); pr.y = pkbf(pv[2], pv[3]);
      *(uint2v*)&myP[c*64 + swk] = pr;
    }

    // Y: row-sum accumulation (independent VALU, hides myP write latency)
    #pragma unroll
    for (int n = 0; n < 4; ++n)
      #pragma unroll
      for (int e = 0; e < 4; ++e)
        lsumY += fexp2(saccY[n][e] * rvSY);

    // X: PV
    short8 pf[2];
    #pragma unroll
    for (int kk = 0; kk < 2; ++kk)
      pf[kk] = *(const short8*)&myP[c*64 + ((kk*32 + g*8) ^ ((c & 7) << 3))];
    __builtin_amdgcn_s_setprio(1);
    #pragma unroll
    for (int n = 0; n < 4; ++n) {
      const int d = n*16 + c;
      const int sw = (d & 7) << 3;
      #pragma unroll
      for (int kk = 0; kk < 2; ++kk) {
        short8 vf = *(const short8*)&sV[cur][d*KB + ((kk*32 + g*8) ^ sw)];
        oaccX[n] = __builtin_amdgcn_mfma_f32_16x16x32_bf16(pf[kk], vf, oaccX[n], 0, 0, 0);
      }
    }
    __builtin_amdgcn_s_setprio(0);

    copyout(abx, kt);
  }

  // ctx(X)
  #pragma unroll
  for (int n = 0; n < 4; ++n)
    #pragma unroll
    for (int e = 0; e < 4; ++e)
      ctx[(bhS + (size_t)(q0x + g*4 + e)) * D_DIM + (size_t)(n*16 + c)] = oaccX[n][e];

  float LmY;
  {
    float v = lsumY;
    v += __shfl_xor(v, 16);
    v += __shfl_xor(v, 32);
    LmY = -__log2f(v);
  }

  // ================= phase C: pass2(Y) =================
  f32x4 oaccY[4];
  #pragma unroll
  for (int n = 0; n < 4; ++n) oaccY[n] = 0.0f;

  for (int kt = 0; kt < NT; ++kt) {
    const int cur = kt & 1;
    write_k(cur);
    write_v(cur);
    if (kt + 1 < NT) { load_k(kt + 1); load_v(kt + 1); }
    barrier_lds();

    short8 kf[4][2];
    read_kf(cur, kf);
    f32x4 sacc[4];
    #pragma unroll
    for (int n = 0; n < 4; ++n) sacc[n] = 0.0f;
    __builtin_amdgcn_s_setprio(1);
    #pragma unroll
    for (int n = 0; n < 4; ++n)
      #pragma unroll
      for (int kk = 0; kk < 2; ++kk)
        sacc[n] = __builtin_amdgcn_mfma_f32_16x16x32_bf16(kf[n][kk], qfY[kk], sacc[n], 0, 0, 0);
    __builtin_amdgcn_s_setprio(0);

    #pragma unroll
    for (int n = 0; n < 4; ++n) {
      f32x4 pv;
      #pragma unroll
      for (int e = 0; e < 4; ++e)
        pv[e] = fexp2(__builtin_fmaf(sacc[n][e], rvSY, LmY));
      const int swk = (n*16 + g*4) ^ ((c & 7) << 3);
      uint2v pr; pr.x = pkbf(pv[0], pv[1]); pr.y = pkbf(pv[2], pv[3]);
      *(uint2v*)&myP[c*64 + swk] = pr;
    }

    short8 pf[2];
    #pragma unroll
    for (int kk = 0; kk < 2; ++kk)
      pf[kk] = *(const short8*)&myP[c*64 + ((kk*32 + g*8) ^ ((c & 7) << 3))];
    __builtin_amdgcn_s_setprio(1);
    #pragma unroll
    for (int n = 0; n < 4; ++n) {
      const int d = n*16 + c;
      const int sw = (d & 7) << 3;
      #pragma unroll
      for (int kk = 0; kk < 2; ++kk) {
        short8 vf = *(const short8*)&sV[cur][d*KB + ((kk*32 + g*8) ^ sw)];
        oaccY[n] = __builtin_amdgcn_mfma_f32_16x16x32_bf16(pf[kk], vf, oaccY[n], 0, 0, 0);
      }
    }
    __builtin_amdgcn_s_setprio(0);

    copyout(aby, kt);
  }

  // ctx(Y)
  #pragma unroll
  for (int n = 0; n < 4; ++n)
    #pragma unroll
    for (int e = 0; e < 4; ++e)
      ctx[(bhS + (size_t)(q0y + g*4 + e)) * D_DIM + (size_t)(n*16 + c)] = oaccY[n][e];
}

extern "C" void kernel_launch(void* const* d_in, const int* in_sizes, int n_in,
                              void* d_out, int out_size, void* d_ws, size_t ws_size,
                              hipStream_t stream) {
  const float* Q = (const float*)d_in[0];
  const float* K = (const float*)d_in[1];
  const float* V = (const float*)d_in[2];
  const int*   M = (const int*)d_in[3];
  float* ctx  = (float*)d_out;
  float* attn = ctx + (size_t)B_DIM * H_DIM * S_DIM * D_DIM;
  dim3 grid(B_DIM * H_DIM * (S_DIM / 256));   // 256 blocks of 512 threads
  sdpa_kernel<<<grid, 512, 0, stream>>>(Q, K, V, M, ctx, attn);
}